// Round 1
// baseline (950.859 us; speedup 1.0000x reference)
//
#include <hip/hip_runtime.h>
#include <stdint.h>

#define D_IN 128
#define D_H  256
#define BMN  32     // node-kernel row tile (was 64): LDS 16.4 KB -> 6 blocks/CU
#define BMG  64     // graph-kernel tile (unchanged)

typedef float f32x4 __attribute__((ext_vector_type(4)));
typedef short s16x8 __attribute__((ext_vector_type(8)));
typedef unsigned int u32x2 __attribute__((ext_vector_type(2)));
typedef unsigned int u32x4 __attribute__((ext_vector_type(4)));

__device__ __forceinline__ unsigned short f2bf(float x) {
  union { float f; uint32_t u; } v; v.f = x;
  uint32_t r = v.u + 0x7fffu + ((v.u >> 16) & 1u);   // RNE
  return (unsigned short)(r >> 16);
}
__device__ __forceinline__ float bf2f(unsigned short u) {
  union { uint32_t u; float f; } v; v.u = (uint32_t)u << 16;
  return v.f;
}
// pack 2 fp32 -> 2 bf16 (RNE), HW instruction when available
__device__ __forceinline__ uint32_t pkbf(float lo, float hi) {
#if __has_builtin(__builtin_amdgcn_cvt_pk_bf16_f32)
  auto r = __builtin_amdgcn_cvt_pk_bf16_f32(lo, hi);
  uint32_t u; __builtin_memcpy(&u, &r, 4); return u;
#else
  return (uint32_t)f2bf(lo) | ((uint32_t)f2bf(hi) << 16);
#endif
}

// ---------------- prep: zero pooled accumulator, cast/transpose weights ----------------
__global__ void prep_kernel(const float* __restrict__ W1, const float* __restrict__ W2,
                            const float* __restrict__ Wg1,
                            float* __restrict__ pooled, unsigned short* __restrict__ W1t,
                            unsigned short* __restrict__ W2t, unsigned short* __restrict__ Wg1t,
                            int pooled_n) {
  int stride = gridDim.x * blockDim.x;
  int tid = blockIdx.x * blockDim.x + threadIdx.x;
  float4 z4 = make_float4(0.f, 0.f, 0.f, 0.f);
  for (int i = tid; i < (pooled_n >> 2); i += stride) ((float4*)pooled)[i] = z4;
  for (int i = tid; i < D_H * D_IN; i += stride) {
    int n = i >> 7, k = i & (D_IN - 1);
    W1t[i] = f2bf(W1[k * D_H + n]);
  }
  for (int i = tid; i < D_H * D_H; i += stride) {
    int n = i >> 8, k = i & (D_H - 1);
    W2t[i]  = f2bf(W2[k * D_H + n]);
    Wg1t[i] = f2bf(Wg1[k * D_H + n]);
  }
}

// ---------------- node MLP + fused segment-sum (one 32-row tile per block) ----------------
// Same proven R2 structure as the 64-row version (swizzles, barrier order, hA
// aliasing, same-wave pooling) but BM halved: LDS 16.4 KB -> residency becomes
// VGPR-capped at 6 blocks/CU (was LDS-capped at 3). acc shrinks to [4][2]
// (-32 VGPR) which funds the tighter __launch_bounds__ regalloc budget.
// hA (8 KB) aliases buf rows 16..31 (buf + 4096 shorts).
__global__ __launch_bounds__(256, 6)
void node_kernel(const float* __restrict__ h, const int* __restrict__ gids,
                 const float* __restrict__ b1, const float* __restrict__ b2,
                 const unsigned short* __restrict__ W1t, const unsigned short* __restrict__ W2t,
                 float* __restrict__ pooled, int nnodes) {
  __shared__ unsigned short buf[BMN * D_H];   // 16 KB: x1/x2 full; hA = buf[4096..8192)
  __shared__ int sgid[BMN];
  const int tid  = threadIdx.x;
  const int lane = tid & 63;
  const int wave = tid >> 6;
  const int lr   = lane & 15;   // row-in-16 (A) / col-in-16 (B,C)
  const int q    = lane >> 4;   // quad
  const int row0 = blockIdx.x * BMN;
  unsigned short* hA = buf + 4096;

  // ---- preload ALL layer-1 A-frags (64 VGPRs): L2 latency hides behind staging+B0
  s16x8 a[4][4];
  #pragma unroll
  for (int ks = 0; ks < 4; ++ks)
    #pragma unroll
    for (int mt = 0; mt < 4; ++mt)
      a[ks][mt] = *(const s16x8*)&W1t[(wave * 64 + mt * 16 + lr) * D_IN + ks * 32 + q * 8];

  if (tid < BMN) {
    int gr = row0 + tid;
    sgid[tid] = (gr < nnodes) ? gids[gr] : -1;   // -1 rows excluded from pooling
  }

  // ---- stage h tile (fp32 -> bf16) into swizzled hA (32 rows x 128 cols)
  #pragma unroll
  for (int i = 0; i < 2; ++i) {
    int gi = tid + i * 256, r = gi >> 4, gc = gi & 15, gr = row0 + r;
    f32x4 v0 = (f32x4){0.f, 0.f, 0.f, 0.f}, v1 = v0;
    if (gr < nnodes) {
      const f32x4* p = (const f32x4*)(h + (size_t)gr * D_IN + gc * 8);
      v0 = __builtin_nontemporal_load(p);       // h is read-once
      v1 = __builtin_nontemporal_load(p + 1);
    }
    u32x4 u;
    u[0] = pkbf(v0[0], v0[1]); u[1] = pkbf(v0[2], v0[3]);
    u[2] = pkbf(v1[0], v1[1]); u[3] = pkbf(v1[2], v1[3]);
    *(u32x4*)&hA[r * D_IN + ((gc ^ (r & 7)) << 3)] = u;
  }
  __syncthreads();   // B0: hA published

  f32x4 acc[4][2];
  #pragma unroll
  for (int mt = 0; mt < 4; ++mt)
    #pragma unroll
    for (int nt = 0; nt < 2; ++nt)
      acc[mt][nt] = (f32x4){0.f, 0.f, 0.f, 0.f};

  // ---- layer 1: x1^T = W1^T(256x128) @ h^T(128x32)
  #pragma unroll
  for (int ks = 0; ks < 4; ++ks) {
    const int kq = ks * 32 + q * 8;
    s16x8 b[2];
    #pragma unroll
    for (int nt = 0; nt < 2; ++nt)
      b[nt] = *(const s16x8*)&hA[(nt * 16 + lr) * D_IN + (((kq >> 3) ^ (lr & 7)) << 3)];
    #pragma unroll
    for (int mt = 0; mt < 4; ++mt)
      #pragma unroll
      for (int nt = 0; nt < 2; ++nt)
        acc[mt][nt] = __builtin_amdgcn_mfma_f32_16x16x32_bf16(a[ks][mt], b[nt], acc[mt][nt], 0, 0, 0);
  }

  // ---- preload W2 half 0 (k=0..127) now: latency spans B1' + epi1 + B1
  #pragma unroll
  for (int ks = 0; ks < 4; ++ks)
    #pragma unroll
    for (int mt = 0; mt < 4; ++mt)
      a[ks][mt] = *(const s16x8*)&W2t[(wave * 64 + mt * 16 + lr) * D_H + ks * 32 + q * 8];

  __syncthreads();   // B1': all hA reads done -> epi1 may overwrite hA region

  // ---- epilogue 1: relu(+b1) -> x1 bf16 swizzled (full 16 KB buf, incl. hA bytes)
  #pragma unroll
  for (int mt = 0; mt < 4; ++mt) {
    int f = wave * 64 + mt * 16 + q * 4;
    float4 bias = *(const float4*)&b1[f];
    #pragma unroll
    for (int nt = 0; nt < 2; ++nt) {
      int nd = nt * 16 + lr;
      u32x2 w;
      w[0] = pkbf(fmaxf(acc[mt][nt][0] + bias.x, 0.f), fmaxf(acc[mt][nt][1] + bias.y, 0.f));
      w[1] = pkbf(fmaxf(acc[mt][nt][2] + bias.z, 0.f), fmaxf(acc[mt][nt][3] + bias.w, 0.f));
      *(u32x2*)&buf[nd * D_H + (((f >> 3) ^ (nd & 7)) << 3) + (f & 7)] = w;
    }
  }
  __syncthreads();   // B1: x1 published

  #pragma unroll
  for (int mt = 0; mt < 4; ++mt)
    #pragma unroll
    for (int nt = 0; nt < 2; ++nt)
      acc[mt][nt] = (f32x4){0.f, 0.f, 0.f, 0.f};

  // ---- layer 2 half 0
  #pragma unroll
  for (int ks = 0; ks < 4; ++ks) {
    const int kq = ks * 32 + q * 8;
    s16x8 b[2];
    #pragma unroll
    for (int nt = 0; nt < 2; ++nt)
      b[nt] = *(const s16x8*)&buf[(nt * 16 + lr) * D_H + (((kq >> 3) ^ (lr & 7)) << 3)];
    #pragma unroll
    for (int mt = 0; mt < 4; ++mt)
      #pragma unroll
      for (int nt = 0; nt < 2; ++nt)
        acc[mt][nt] = __builtin_amdgcn_mfma_f32_16x16x32_bf16(a[ks][mt], b[nt], acc[mt][nt], 0, 0, 0);
  }
  // ---- layer 2 half 1 (reload A into same regs)
  #pragma unroll
  for (int ks = 0; ks < 4; ++ks)
    #pragma unroll
    for (int mt = 0; mt < 4; ++mt)
      a[ks][mt] = *(const s16x8*)&W2t[(wave * 64 + mt * 16 + lr) * D_H + 128 + ks * 32 + q * 8];
  #pragma unroll
  for (int ks = 0; ks < 4; ++ks) {
    const int kq = 128 + ks * 32 + q * 8;
    s16x8 b[2];
    #pragma unroll
    for (int nt = 0; nt < 2; ++nt)
      b[nt] = *(const s16x8*)&buf[(nt * 16 + lr) * D_H + (((kq >> 3) ^ (lr & 7)) << 3)];
    #pragma unroll
    for (int mt = 0; mt < 4; ++mt)
      #pragma unroll
      for (int nt = 0; nt < 2; ++nt)
        acc[mt][nt] = __builtin_amdgcn_mfma_f32_16x16x32_bf16(a[ks][mt], b[nt], acc[mt][nt], 0, 0, 0);
  }
  __syncthreads();   // B2: all x1 reads done -> overwrite with x2

  // ---- epilogue 2: relu(+b2) -> x2 bf16 into buf (same swizzle)
  #pragma unroll
  for (int mt = 0; mt < 4; ++mt) {
    int f = wave * 64 + mt * 16 + q * 4;
    float4 bias = *(const float4*)&b2[f];
    #pragma unroll
    for (int nt = 0; nt < 2; ++nt) {
      int nd = nt * 16 + lr;
      u32x2 w;
      w[0] = pkbf(fmaxf(acc[mt][nt][0] + bias.x, 0.f), fmaxf(acc[mt][nt][1] + bias.y, 0.f));
      w[1] = pkbf(fmaxf(acc[mt][nt][2] + bias.z, 0.f), fmaxf(acc[mt][nt][3] + bias.w, 0.f));
      *(u32x2*)&buf[nd * D_H + (((f >> 3) ^ (nd & 7)) << 3) + (f & 7)] = w;
    }
  }

  // ---- pooling: thread tid reads feature tid = own wave's stripe (same-wave
  //      LDS program order, no barrier). Sorted gids -> run detection.
  {
    const int hi = tid >> 3, lo = tid & 7;
    float racc = 0.f;
    for (int r = 0; r < BMN; ++r) {
      int g = sgid[r];                    // wave-uniform
      if (g >= 0) {
        racc += bf2f(buf[r * D_H + ((hi ^ (r & 7)) << 3) + lo]);
        if (r == BMN - 1 || sgid[r + 1] != g) {
          atomicAdd(&pooled[g * D_H + tid], racc);
          racc = 0.f;
        }
      }
    }
  }
}

// ---------------- graph MLP: swizzled 32 KB LDS, bf16 y, conflict-free ----------------
__global__ __launch_bounds__(256, 4)
void graph_kernel(const float* __restrict__ pooled, const float* __restrict__ bg1,
                  const unsigned short* __restrict__ Wg1t, const float* __restrict__ Wg2,
                  const float* __restrict__ bg2, float* __restrict__ out, int ngraphs) {
  __shared__ unsigned short pA[BMG * D_H];   // 32 KB swizzled; pooled-bf16 then y-bf16
  const int tid  = threadIdx.x;
  const int lane = tid & 63;
  const int wave = tid >> 6;
  const int lr   = lane & 15;
  const int q    = lane >> 4;
  const int g0   = blockIdx.x * BMG;

  #pragma unroll
  for (int i = 0; i < 8; ++i) {
    int gi = tid + i * 256, r = gi >> 5, gc = gi & 31;
    int gr = g0 + r;
    f32x4 v0 = (f32x4){0.f, 0.f, 0.f, 0.f}, v1 = v0;
    if (gr < ngraphs) {
      const f32x4* p = (const f32x4*)(pooled + (size_t)gr * D_H + gc * 8);
      v0 = p[0]; v1 = p[1];
    }
    u32x4 u;
    u[0] = pkbf(v0[0], v0[1]); u[1] = pkbf(v0[2], v0[3]);
    u[2] = pkbf(v1[0], v1[1]); u[3] = pkbf(v1[2], v1[3]);
    *(u32x4*)&pA[r * D_H + (((gc & 7) ^ (r & 7)) << 3) + ((gc & 24) << 3)] = u;
  }
  __syncthreads();

  f32x4 acc[4][4];
  #pragma unroll
  for (int mt = 0; mt < 4; ++mt)
    #pragma unroll
    for (int nt = 0; nt < 4; ++nt)
      acc[mt][nt] = (f32x4){0.f, 0.f, 0.f, 0.f};

  #pragma unroll
  for (int ks = 0; ks < 8; ++ks) {
    const int kq = ks * 32 + q * 8;
    s16x8 a[4], b[4];
    #pragma unroll
    for (int mt = 0; mt < 4; ++mt)
      a[mt] = *(const s16x8*)&Wg1t[(wave * 64 + mt * 16 + lr) * D_H + kq];
    #pragma unroll
    for (int nt = 0; nt < 4; ++nt) {
      int row = nt * 16 + lr, gw = kq >> 3;
      b[nt] = *(const s16x8*)&pA[row * D_H + (((gw & 7) ^ (row & 7)) << 3) + ((gw & 24) << 3)];
    }
    #pragma unroll
    for (int mt = 0; mt < 4; ++mt)
      #pragma unroll
      for (int nt = 0; nt < 4; ++nt)
        acc[mt][nt] = __builtin_amdgcn_mfma_f32_16x16x32_bf16(a[mt], b[nt], acc[mt][nt], 0, 0, 0);
  }
  __syncthreads();   // all pA reads done; overwrite with y

  #pragma unroll
  for (int mt = 0; mt < 4; ++mt) {
    int f = wave * 64 + mt * 16 + q * 4;
    float4 bias = *(const float4*)&bg1[f];
    #pragma unroll
    for (int nt = 0; nt < 4; ++nt) {
      int nd = nt * 16 + lr;
      u32x2 w;
      w[0] = pkbf(fmaxf(acc[mt][nt][0] + bias.x, 0.f), fmaxf(acc[mt][nt][1] + bias.y, 0.f));
      w[1] = pkbf(fmaxf(acc[mt][nt][2] + bias.z, 0.f), fmaxf(acc[mt][nt][3] + bias.w, 0.f));
      int gw = f >> 3;
      *(u32x2*)&pA[nd * D_H + (((gw & 7) ^ (nd & 7)) << 3) + ((gw & 24) << 3) + (f & 7)] = w;
    }
  }
  __syncthreads();

  int gloc = tid >> 2;
  int part = tid & 3;
  float p = 0.f;
  #pragma unroll 8
  for (int i = 0; i < 32; ++i) {
    int f2 = part + 4 * i;
    int hw = 2 * f2;
    int gw = hw >> 3;
    uint32_t wv = *(const uint32_t*)&pA[gloc * D_H + (((gw & 7) ^ (gloc & 7)) << 3) +
                                        ((gw & 24) << 3) + (hw & 7)];
    float2 wg = ((const float2*)Wg2)[f2];
    p += bf2f((unsigned short)(wv & 0xffffu)) * wg.x +
         bf2f((unsigned short)(wv >> 16)) * wg.y;
  }
  p += __shfl_xor(p, 1);
  p += __shfl_xor(p, 2);
  if (part == 0 && (g0 + gloc) < ngraphs)
    out[g0 + gloc] = p + bg2[0];
}

extern "C" void kernel_launch(void* const* d_in, const int* in_sizes, int n_in,
                              void* d_out, int out_size, void* d_ws, size_t ws_size,
                              hipStream_t stream) {
  const float* h   = (const float*)d_in[0];
  const int*   gid = (const int*)d_in[1];
  const float* W1  = (const float*)d_in[3];
  const float* b1  = (const float*)d_in[4];
  const float* W2  = (const float*)d_in[5];
  const float* b2  = (const float*)d_in[6];
  const float* Wg1 = (const float*)d_in[7];
  const float* bg1 = (const float*)d_in[8];
  const float* Wg2 = (const float*)d_in[9];
  const float* bg2 = (const float*)d_in[10];
  float* out = (float*)d_out;

  const int N = in_sizes[1];
  const int G = out_size;

  char* ws = (char*)d_ws;
  float* pooled = (float*)ws;                                   // G*256*4 = 20.48 MB
  size_t off = (size_t)G * D_H * sizeof(float);
  unsigned short* W1t  = (unsigned short*)(ws + off); off += (size_t)D_H * D_IN * 2;
  unsigned short* W2t  = (unsigned short*)(ws + off); off += (size_t)D_H * D_H * 2;
  unsigned short* Wg1t = (unsigned short*)(ws + off);

  prep_kernel<<<512, 256, 0, stream>>>(W1, W2, Wg1, pooled, W1t, W2t, Wg1t, G * D_H);
  node_kernel<<<(N + BMN - 1) / BMN, 256, 0, stream>>>(h, gid, b1, b2, W1t, W2t, pooled, N);
  graph_kernel<<<(G + BMG - 1) / BMG, 256, 0, stream>>>(pooled, bg1, Wg1t, Wg2, bg2, out, G);
}

// Round 3
// 675.231 us; speedup vs baseline: 1.4082x; 1.4082x over previous
//
#include <hip/hip_runtime.h>
#include <stdint.h>

#define D_IN 128
#define D_H  256
#define BMN  32     // node-kernel row tile: LDS 16.4 KB
#define BMG  64     // graph-kernel tile (unchanged)

typedef float f32x4 __attribute__((ext_vector_type(4)));
typedef short s16x8 __attribute__((ext_vector_type(8)));
typedef unsigned int u32x2 __attribute__((ext_vector_type(2)));
typedef unsigned int u32x4 __attribute__((ext_vector_type(4)));

__device__ __forceinline__ unsigned short f2bf(float x) {
  union { float f; uint32_t u; } v; v.f = x;
  uint32_t r = v.u + 0x7fffu + ((v.u >> 16) & 1u);   // RNE
  return (unsigned short)(r >> 16);
}
__device__ __forceinline__ float bf2f(unsigned short u) {
  union { uint32_t u; float f; } v; v.u = (uint32_t)u << 16;
  return v.f;
}
// pack 2 fp32 -> 2 bf16 (RNE), HW instruction when available
__device__ __forceinline__ uint32_t pkbf(float lo, float hi) {
#if __has_builtin(__builtin_amdgcn_cvt_pk_bf16_f32)
  auto r = __builtin_amdgcn_cvt_pk_bf16_f32(lo, hi);
  uint32_t u; __builtin_memcpy(&u, &r, 4); return u;
#else
  return (uint32_t)f2bf(lo) | ((uint32_t)f2bf(hi) << 16);
#endif
}

// ---------------- prep: zero pooled accumulator, cast/transpose weights ----------------
__global__ void prep_kernel(const float* __restrict__ W1, const float* __restrict__ W2,
                            const float* __restrict__ Wg1,
                            float* __restrict__ pooled, unsigned short* __restrict__ W1t,
                            unsigned short* __restrict__ W2t, unsigned short* __restrict__ Wg1t,
                            int pooled_n) {
  int stride = gridDim.x * blockDim.x;
  int tid = blockIdx.x * blockDim.x + threadIdx.x;
  float4 z4 = make_float4(0.f, 0.f, 0.f, 0.f);
  for (int i = tid; i < (pooled_n >> 2); i += stride) ((float4*)pooled)[i] = z4;
  for (int i = tid; i < D_H * D_IN; i += stride) {
    int n = i >> 7, k = i & (D_IN - 1);
    W1t[i] = f2bf(W1[k * D_H + n]);
  }
  for (int i = tid; i < D_H * D_H; i += stride) {
    int n = i >> 8, k = i & (D_H - 1);
    W2t[i]  = f2bf(W2[k * D_H + n]);
    Wg1t[i] = f2bf(Wg1[k * D_H + n]);
  }
}

// ---------------- node MLP + fused segment-sum (one 32-row tile per block) ----------------
// R1 post-mortem: __launch_bounds__(256,6) with a[4][4] preload (64 VGPR) forced
// scratch spills (VGPR 40, FETCH 699 MB, WRITE 1.14 GB). Fix: rotating a[2][4]
// weight buffer (32 VGPR) prefetching ks+2 while consuming ks. Genuine demand
// ~95-100 regs (32 a + 32 acc-AGPR + temps) fits 512/5 = 102 -> (256,5),
// 5 blocks/CU, no spills. Layer-1 steps ks=2,3 prefetch W2 ks=0,1 so the W2
// latency still spans B1' + epi1 + B1 as in the proven R0 schedule.
// hA (8 KB) aliases buf rows 16..31 (buf + 4096 shorts).
__global__ __launch_bounds__(256, 5)
void node_kernel(const float* __restrict__ h, const int* __restrict__ gids,
                 const float* __restrict__ b1, const float* __restrict__ b2,
                 const unsigned short* __restrict__ W1t, const unsigned short* __restrict__ W2t,
                 float* __restrict__ pooled, int nnodes) {
  __shared__ unsigned short buf[BMN * D_H];   // 16 KB: x1/x2 full; hA = buf[4096..8192)
  __shared__ int sgid[BMN];
  const int tid  = threadIdx.x;
  const int lane = tid & 63;
  const int wave = tid >> 6;
  const int lr   = lane & 15;   // row-in-16 (A) / col-in-16 (B,C)
  const int q    = lane >> 4;   // quad
  const int row0 = blockIdx.x * BMN;
  unsigned short* hA = buf + 4096;

  const unsigned short* w1base = W1t + (wave * 64 + lr) * D_IN + q * 8;
  const unsigned short* w2base = W2t + (wave * 64 + lr) * D_H + q * 8;

  // ---- rotating 2-deep weight fragment buffer (32 VGPR instead of 64)
  s16x8 a[2][4];
  #pragma unroll
  for (int mt = 0; mt < 4; ++mt) a[0][mt] = *(const s16x8*)(w1base + mt * 16 * D_IN + 0 * 32);
  #pragma unroll
  for (int mt = 0; mt < 4; ++mt) a[1][mt] = *(const s16x8*)(w1base + mt * 16 * D_IN + 1 * 32);

  if (tid < BMN) {
    int gr = row0 + tid;
    sgid[tid] = (gr < nnodes) ? gids[gr] : -1;   // -1 rows excluded from pooling
  }

  // ---- stage h tile (fp32 -> bf16) into swizzled hA (32 rows x 128 cols)
  #pragma unroll
  for (int i = 0; i < 2; ++i) {
    int gi = tid + i * 256, r = gi >> 4, gc = gi & 15, gr = row0 + r;
    f32x4 v0 = (f32x4){0.f, 0.f, 0.f, 0.f}, v1 = v0;
    if (gr < nnodes) {
      const f32x4* p = (const f32x4*)(h + (size_t)gr * D_IN + gc * 8);
      v0 = __builtin_nontemporal_load(p);       // h is read-once
      v1 = __builtin_nontemporal_load(p + 1);
    }
    u32x4 u;
    u[0] = pkbf(v0[0], v0[1]); u[1] = pkbf(v0[2], v0[3]);
    u[2] = pkbf(v1[0], v1[1]); u[3] = pkbf(v1[2], v1[3]);
    *(u32x4*)&hA[r * D_IN + ((gc ^ (r & 7)) << 3)] = u;
  }
  __syncthreads();   // B0: hA published

  f32x4 acc[4][2];
  #pragma unroll
  for (int mt = 0; mt < 4; ++mt)
    #pragma unroll
    for (int nt = 0; nt < 2; ++nt)
      acc[mt][nt] = (f32x4){0.f, 0.f, 0.f, 0.f};

  // ---- layer 1: x1^T = W1^T(256x128) @ h^T(128x32); prefetch rotation:
  //      ks=0,1 refill with W1 ks+2; ks=2,3 refill with W2 ks=0,1 (spans barriers)
  #pragma unroll
  for (int ks = 0; ks < 4; ++ks) {
    const int kq = ks * 32 + q * 8;
    s16x8 b[2];
    #pragma unroll
    for (int nt = 0; nt < 2; ++nt)
      b[nt] = *(const s16x8*)&hA[(nt * 16 + lr) * D_IN + (((kq >> 3) ^ (lr & 7)) << 3)];
    #pragma unroll
    for (int mt = 0; mt < 4; ++mt)
      #pragma unroll
      for (int nt = 0; nt < 2; ++nt)
        acc[mt][nt] = __builtin_amdgcn_mfma_f32_16x16x32_bf16(a[ks & 1][mt], b[nt], acc[mt][nt], 0, 0, 0);
    if (ks < 2) {
      #pragma unroll
      for (int mt = 0; mt < 4; ++mt)
        a[ks & 1][mt] = *(const s16x8*)(w1base + mt * 16 * D_IN + (ks + 2) * 32);
    } else {
      #pragma unroll
      for (int mt = 0; mt < 4; ++mt)
        a[ks & 1][mt] = *(const s16x8*)(w2base + mt * 16 * D_H + (ks - 2) * 32);
    }
  }

  __syncthreads();   // B1': all hA reads done -> epi1 may overwrite hA region

  // ---- epilogue 1: relu(+b1) -> x1 bf16 swizzled (full 16 KB buf, incl. hA bytes)
  #pragma unroll
  for (int mt = 0; mt < 4; ++mt) {
    int f = wave * 64 + mt * 16 + q * 4;
    float4 bias = *(const float4*)&b1[f];
    #pragma unroll
    for (int nt = 0; nt < 2; ++nt) {
      int nd = nt * 16 + lr;
      u32x2 w;
      w[0] = pkbf(fmaxf(acc[mt][nt][0] + bias.x, 0.f), fmaxf(acc[mt][nt][1] + bias.y, 0.f));
      w[1] = pkbf(fmaxf(acc[mt][nt][2] + bias.z, 0.f), fmaxf(acc[mt][nt][3] + bias.w, 0.f));
      *(u32x2*)&buf[nd * D_H + (((f >> 3) ^ (nd & 7)) << 3) + (f & 7)] = w;
    }
  }
  __syncthreads();   // B1: x1 published

  #pragma unroll
  for (int mt = 0; mt < 4; ++mt)
    #pragma unroll
    for (int nt = 0; nt < 2; ++nt)
      acc[mt][nt] = (f32x4){0.f, 0.f, 0.f, 0.f};

  // ---- layer 2: unified 8 k-steps; a[ks&1] holds W2 ks (prefetched 2 ahead)
  #pragma unroll
  for (int ks = 0; ks < 8; ++ks) {
    const int kq = ks * 32 + q * 8;
    s16x8 b[2];
    #pragma unroll
    for (int nt = 0; nt < 2; ++nt)
      b[nt] = *(const s16x8*)&buf[(nt * 16 + lr) * D_H + (((kq >> 3) ^ (lr & 7)) << 3)];
    #pragma unroll
    for (int mt = 0; mt < 4; ++mt)
      #pragma unroll
      for (int nt = 0; nt < 2; ++nt)
        acc[mt][nt] = __builtin_amdgcn_mfma_f32_16x16x32_bf16(a[ks & 1][mt], b[nt], acc[mt][nt], 0, 0, 0);
    if (ks < 6) {
      #pragma unroll
      for (int mt = 0; mt < 4; ++mt)
        a[ks & 1][mt] = *(const s16x8*)(w2base + mt * 16 * D_H + (ks + 2) * 32);
    }
  }
  __syncthreads();   // B2: all x1 reads done -> overwrite with x2

  // ---- epilogue 2: relu(+b2) -> x2 bf16 into buf (same swizzle)
  #pragma unroll
  for (int mt = 0; mt < 4; ++mt) {
    int f = wave * 64 + mt * 16 + q * 4;
    float4 bias = *(const float4*)&b2[f];
    #pragma unroll
    for (int nt = 0; nt < 2; ++nt) {
      int nd = nt * 16 + lr;
      u32x2 w;
      w[0] = pkbf(fmaxf(acc[mt][nt][0] + bias.x, 0.f), fmaxf(acc[mt][nt][1] + bias.y, 0.f));
      w[1] = pkbf(fmaxf(acc[mt][nt][2] + bias.z, 0.f), fmaxf(acc[mt][nt][3] + bias.w, 0.f));
      *(u32x2*)&buf[nd * D_H + (((f >> 3) ^ (nd & 7)) << 3) + (f & 7)] = w;
    }
  }

  // ---- pooling: thread tid reads feature tid = own wave's stripe (same-wave
  //      LDS program order, no barrier). Sorted gids -> run detection.
  {
    const int hi = tid >> 3, lo = tid & 7;
    float racc = 0.f;
    for (int r = 0; r < BMN; ++r) {
      int g = sgid[r];                    // wave-uniform
      if (g >= 0) {
        racc += bf2f(buf[r * D_H + ((hi ^ (r & 7)) << 3) + lo]);
        if (r == BMN - 1 || sgid[r + 1] != g) {
          atomicAdd(&pooled[g * D_H + tid], racc);
          racc = 0.f;
        }
      }
    }
  }
}

// ---------------- graph MLP: swizzled 32 KB LDS, bf16 y, conflict-free ----------------
__global__ __launch_bounds__(256, 4)
void graph_kernel(const float* __restrict__ pooled, const float* __restrict__ bg1,
                  const unsigned short* __restrict__ Wg1t, const float* __restrict__ Wg2,
                  const float* __restrict__ bg2, float* __restrict__ out, int ngraphs) {
  __shared__ unsigned short pA[BMG * D_H];   // 32 KB swizzled; pooled-bf16 then y-bf16
  const int tid  = threadIdx.x;
  const int lane = tid & 63;
  const int wave = tid >> 6;
  const int lr   = lane & 15;
  const int q    = lane >> 4;
  const int g0   = blockIdx.x * BMG;

  #pragma unroll
  for (int i = 0; i < 8; ++i) {
    int gi = tid + i * 256, r = gi >> 5, gc = gi & 31;
    int gr = g0 + r;
    f32x4 v0 = (f32x4){0.f, 0.f, 0.f, 0.f}, v1 = v0;
    if (gr < ngraphs) {
      const f32x4* p = (const f32x4*)(pooled + (size_t)gr * D_H + gc * 8);
      v0 = p[0]; v1 = p[1];
    }
    u32x4 u;
    u[0] = pkbf(v0[0], v0[1]); u[1] = pkbf(v0[2], v0[3]);
    u[2] = pkbf(v1[0], v1[1]); u[3] = pkbf(v1[2], v1[3]);
    *(u32x4*)&pA[r * D_H + (((gc & 7) ^ (r & 7)) << 3) + ((gc & 24) << 3)] = u;
  }
  __syncthreads();

  f32x4 acc[4][4];
  #pragma unroll
  for (int mt = 0; mt < 4; ++mt)
    #pragma unroll
    for (int nt = 0; nt < 4; ++nt)
      acc[mt][nt] = (f32x4){0.f, 0.f, 0.f, 0.f};

  #pragma unroll
  for (int ks = 0; ks < 8; ++ks) {
    const int kq = ks * 32 + q * 8;
    s16x8 a[4], b[4];
    #pragma unroll
    for (int mt = 0; mt < 4; ++mt)
      a[mt] = *(const s16x8*)&Wg1t[(wave * 64 + mt * 16 + lr) * D_H + kq];
    #pragma unroll
    for (int nt = 0; nt < 4; ++nt) {
      int row = nt * 16 + lr, gw = kq >> 3;
      b[nt] = *(const s16x8*)&pA[row * D_H + (((gw & 7) ^ (row & 7)) << 3) + ((gw & 24) << 3)];
    }
    #pragma unroll
    for (int mt = 0; mt < 4; ++mt)
      #pragma unroll
      for (int nt = 0; nt < 4; ++nt)
        acc[mt][nt] = __builtin_amdgcn_mfma_f32_16x16x32_bf16(a[mt], b[nt], acc[mt][nt], 0, 0, 0);
  }
  __syncthreads();   // all pA reads done; overwrite with y

  #pragma unroll
  for (int mt = 0; mt < 4; ++mt) {
    int f = wave * 64 + mt * 16 + q * 4;
    float4 bias = *(const float4*)&bg1[f];
    #pragma unroll
    for (int nt = 0; nt < 4; ++nt) {
      int nd = nt * 16 + lr;
      u32x2 w;
      w[0] = pkbf(fmaxf(acc[mt][nt][0] + bias.x, 0.f), fmaxf(acc[mt][nt][1] + bias.y, 0.f));
      w[1] = pkbf(fmaxf(acc[mt][nt][2] + bias.z, 0.f), fmaxf(acc[mt][nt][3] + bias.w, 0.f));
      int gw = f >> 3;
      *(u32x2*)&pA[nd * D_H + (((gw & 7) ^ (nd & 7)) << 3) + ((gw & 24) << 3) + (f & 7)] = w;
    }
  }
  __syncthreads();

  int gloc = tid >> 2;
  int part = tid & 3;
  float p = 0.f;
  #pragma unroll 8
  for (int i = 0; i < 32; ++i) {
    int f2 = part + 4 * i;
    int hw = 2 * f2;
    int gw = hw >> 3;
    uint32_t wv = *(const uint32_t*)&pA[gloc * D_H + (((gw & 7) ^ (gloc & 7)) << 3) +
                                        ((gw & 24) << 3) + (hw & 7)];
    float2 wg = ((const float2*)Wg2)[f2];
    p += bf2f((unsigned short)(wv & 0xffffu)) * wg.x +
         bf2f((unsigned short)(wv >> 16)) * wg.y;
  }
  p += __shfl_xor(p, 1);
  p += __shfl_xor(p, 2);
  if (part == 0 && (g0 + gloc) < ngraphs)
    out[g0 + gloc] = p + bg2[0];
}

extern "C" void kernel_launch(void* const* d_in, const int* in_sizes, int n_in,
                              void* d_out, int out_size, void* d_ws, size_t ws_size,
                              hipStream_t stream) {
  const float* h   = (const float*)d_in[0];
  const int*   gid = (const int*)d_in[1];
  const float* W1  = (const float*)d_in[3];
  const float* b1  = (const float*)d_in[4];
  const float* W2  = (const float*)d_in[5];
  const float* b2  = (const float*)d_in[6];
  const float* Wg1 = (const float*)d_in[7];
  const float* bg1 = (const float*)d_in[8];
  const float* Wg2 = (const float*)d_in[9];
  const float* bg2 = (const float*)d_in[10];
  float* out = (float*)d_out;

  const int N = in_sizes[1];
  const int G = out_size;

  char* ws = (char*)d_ws;
  float* pooled = (float*)ws;                                   // G*256*4 = 20.48 MB
  size_t off = (size_t)G * D_H * sizeof(float);
  unsigned short* W1t  = (unsigned short*)(ws + off); off += (size_t)D_H * D_IN * 2;
  unsigned short* W2t  = (unsigned short*)(ws + off); off += (size_t)D_H * D_H * 2;
  unsigned short* Wg1t = (unsigned short*)(ws + off);

  prep_kernel<<<512, 256, 0, stream>>>(W1, W2, Wg1, pooled, W1t, W2t, Wg1t, G * D_H);
  node_kernel<<<(N + BMN - 1) / BMN, 256, 0, stream>>>(h, gid, b1, b2, W1t, W2t, pooled, N);
  graph_kernel<<<(G + BMG - 1) / BMG, 256, 0, stream>>>(pooled, bg1, Wg1t, Wg2, bg2, out, G);
}

// Round 4
// 633.792 us; speedup vs baseline: 1.5003x; 1.0654x over previous
//
#include <hip/hip_runtime.h>
#include <stdint.h>

#define D_IN 128
#define D_H  256
#define BM   64     // node row tile (R0-proven); BM=32 regressed (R3: latency/block fixed)
#define BMG  64     // graph-kernel tile

typedef float f32x4 __attribute__((ext_vector_type(4)));
typedef short s16x8 __attribute__((ext_vector_type(8)));
typedef unsigned int u32x2 __attribute__((ext_vector_type(2)));
typedef unsigned int u32x4 __attribute__((ext_vector_type(4)));

__device__ __forceinline__ unsigned short f2bf(float x) {
  union { float f; uint32_t u; } v; v.f = x;
  uint32_t r = v.u + 0x7fffu + ((v.u >> 16) & 1u);   // RNE
  return (unsigned short)(r >> 16);
}
__device__ __forceinline__ float bf2f(unsigned short u) {
  union { uint32_t u; float f; } v; v.u = (uint32_t)u << 16;
  return v.f;
}
// pack 2 fp32 -> 2 bf16 (RNE), HW instruction when available
__device__ __forceinline__ uint32_t pkbf(float lo, float hi) {
#if __has_builtin(__builtin_amdgcn_cvt_pk_bf16_f32)
  auto r = __builtin_amdgcn_cvt_pk_bf16_f32(lo, hi);
  uint32_t u; __builtin_memcpy(&u, &r, 4); return u;
#else
  return (uint32_t)f2bf(lo) | ((uint32_t)f2bf(hi) << 16);
#endif
}

// ---------------- prep: zero pooled accumulator, cast/transpose weights ----------------
__global__ void prep_kernel(const float* __restrict__ W1, const float* __restrict__ W2,
                            const float* __restrict__ Wg1,
                            float* __restrict__ pooled, unsigned short* __restrict__ W1t,
                            unsigned short* __restrict__ W2t, unsigned short* __restrict__ Wg1t,
                            int pooled_n) {
  int stride = gridDim.x * blockDim.x;
  int tid = blockIdx.x * blockDim.x + threadIdx.x;
  float4 z4 = make_float4(0.f, 0.f, 0.f, 0.f);
  for (int i = tid; i < (pooled_n >> 2); i += stride) ((float4*)pooled)[i] = z4;
  for (int i = tid; i < D_H * D_IN; i += stride) {
    int n = i >> 7, k = i & (D_IN - 1);
    W1t[i] = f2bf(W1[k * D_H + n]);
  }
  for (int i = tid; i < D_H * D_H; i += stride) {
    int n = i >> 8, k = i & (D_H - 1);
    W2t[i]  = f2bf(W2[k * D_H + n]);
    Wg1t[i] = f2bf(Wg1[k * D_H + n]);
  }
}

// ---------------- node MLP + fused segment-sum (R0 structure, 4 blocks/CU) ----------------
// Exactly the R0-proven BM=64 schedule (33 KB LDS: hA aliases buf upper half,
// barriers B0/B1'/B1/B2, same swizzles, own-stripe pooling) with two changes:
//  1. rotating a[2][4] weight buffer (R3-proven correct; -32 VGPR vs a[4][4])
//     -> unified demand ~116-124 regs, fits __launch_bounds__(256,4) = 128 cap
//     -> 4 blocks/CU (R0 was 148 regs -> 3 blocks/CU). At BM=64 each refill has
//     ~160 cy of MFMA cover (16 MFMA/k-step, 2-deep), unlike R3's exposed 80.
//  2. pooling vectorized: b64 reads, 4 feats x 4 row-groups per wave, 16 iters
//     (was 64 scalar iters). Still reads only the own wave's feature stripe ->
//     same-wave LDS program order, no extra barrier.
__global__ __launch_bounds__(256, 4)
void node_kernel(const float* __restrict__ h, const int* __restrict__ gids,
                 const float* __restrict__ b1, const float* __restrict__ b2,
                 const unsigned short* __restrict__ W1t, const unsigned short* __restrict__ W2t,
                 float* __restrict__ pooled, int nnodes) {
  __shared__ unsigned short buf[BM * D_H];   // 32 KB: x1/x2 full; hA = buf[8192..16384)
  __shared__ int sgid[BM];
  const int tid  = threadIdx.x;
  const int lane = tid & 63;
  const int wave = tid >> 6;
  const int lr   = lane & 15;   // row-in-16 (A) / col-in-16 (B,C)
  const int q    = lane >> 4;   // quad
  const int row0 = blockIdx.x * BM;
  unsigned short* hA = buf + 8192;

  const unsigned short* w1base = W1t + (wave * 64 + lr) * D_IN + q * 8;
  const unsigned short* w2base = W2t + (wave * 64 + lr) * D_H + q * 8;

  // ---- rotating 2-deep weight fragment buffer (32 VGPR instead of 64)
  s16x8 a[2][4];
  #pragma unroll
  for (int mt = 0; mt < 4; ++mt) a[0][mt] = *(const s16x8*)(w1base + mt * 16 * D_IN + 0 * 32);
  #pragma unroll
  for (int mt = 0; mt < 4; ++mt) a[1][mt] = *(const s16x8*)(w1base + mt * 16 * D_IN + 1 * 32);

  if (tid < BM) {
    int gr = row0 + tid;
    sgid[tid] = (gr < nnodes) ? gids[gr] : -1;   // -1 rows excluded from pooling
  }

  // ---- stage h tile (fp32 -> bf16) into swizzled hA
  #pragma unroll
  for (int i = 0; i < 4; ++i) {
    int gi = tid + i * 256, r = gi >> 4, gc = gi & 15, gr = row0 + r;
    f32x4 v0 = (f32x4){0.f, 0.f, 0.f, 0.f}, v1 = v0;
    if (gr < nnodes) {
      const f32x4* p = (const f32x4*)(h + (size_t)gr * D_IN + gc * 8);
      v0 = __builtin_nontemporal_load(p);       // h is read-once
      v1 = __builtin_nontemporal_load(p + 1);
    }
    u32x4 u;
    u[0] = pkbf(v0[0], v0[1]); u[1] = pkbf(v0[2], v0[3]);
    u[2] = pkbf(v1[0], v1[1]); u[3] = pkbf(v1[2], v1[3]);
    *(u32x4*)&hA[r * D_IN + ((gc ^ (r & 7)) << 3)] = u;
  }
  __syncthreads();   // B0: hA published

  f32x4 acc[4][4];
  #pragma unroll
  for (int mt = 0; mt < 4; ++mt)
    #pragma unroll
    for (int nt = 0; nt < 4; ++nt)
      acc[mt][nt] = (f32x4){0.f, 0.f, 0.f, 0.f};

  // ---- layer 1: x1^T = W1^T(256x128) @ h^T(128x64); rotation:
  //      ks=0,1 refill with W1 ks+2; ks=2,3 refill with W2 ks=0,1
  //      (W2 latency spans B1' + epi1 + B1 as in the proven R0 schedule)
  #pragma unroll
  for (int ks = 0; ks < 4; ++ks) {
    const int kq = ks * 32 + q * 8;
    s16x8 b[4];
    #pragma unroll
    for (int nt = 0; nt < 4; ++nt)
      b[nt] = *(const s16x8*)&hA[(nt * 16 + lr) * D_IN + (((kq >> 3) ^ (lr & 7)) << 3)];
    #pragma unroll
    for (int mt = 0; mt < 4; ++mt)
      #pragma unroll
      for (int nt = 0; nt < 4; ++nt)
        acc[mt][nt] = __builtin_amdgcn_mfma_f32_16x16x32_bf16(a[ks & 1][mt], b[nt], acc[mt][nt], 0, 0, 0);
    if (ks < 2) {
      #pragma unroll
      for (int mt = 0; mt < 4; ++mt)
        a[ks & 1][mt] = *(const s16x8*)(w1base + mt * 16 * D_IN + (ks + 2) * 32);
    } else {
      #pragma unroll
      for (int mt = 0; mt < 4; ++mt)
        a[ks & 1][mt] = *(const s16x8*)(w2base + mt * 16 * D_H + (ks - 2) * 32);
    }
  }

  __syncthreads();   // B1': all hA reads done -> epi1 may overwrite hA region

  // ---- epilogue 1: relu(+b1) -> x1 bf16 swizzled (full 32 KB buf, incl. hA bytes)
  #pragma unroll
  for (int mt = 0; mt < 4; ++mt) {
    int f = wave * 64 + mt * 16 + q * 4;
    float4 bias = *(const float4*)&b1[f];
    #pragma unroll
    for (int nt = 0; nt < 4; ++nt) {
      int nd = nt * 16 + lr;
      u32x2 w;
      w[0] = pkbf(fmaxf(acc[mt][nt][0] + bias.x, 0.f), fmaxf(acc[mt][nt][1] + bias.y, 0.f));
      w[1] = pkbf(fmaxf(acc[mt][nt][2] + bias.z, 0.f), fmaxf(acc[mt][nt][3] + bias.w, 0.f));
      *(u32x2*)&buf[nd * D_H + (((f >> 3) ^ (nd & 7)) << 3) + (f & 7)] = w;
    }
  }
  __syncthreads();   // B1: x1 published

  #pragma unroll
  for (int mt = 0; mt < 4; ++mt)
    #pragma unroll
    for (int nt = 0; nt < 4; ++nt)
      acc[mt][nt] = (f32x4){0.f, 0.f, 0.f, 0.f};

  // ---- layer 2: 8 unified k-steps; a[ks&1] holds W2 ks (prefetched 2 ahead)
  #pragma unroll
  for (int ks = 0; ks < 8; ++ks) {
    const int kq = ks * 32 + q * 8;
    s16x8 b[4];
    #pragma unroll
    for (int nt = 0; nt < 4; ++nt)
      b[nt] = *(const s16x8*)&buf[(nt * 16 + lr) * D_H + (((kq >> 3) ^ (lr & 7)) << 3)];
    #pragma unroll
    for (int mt = 0; mt < 4; ++mt)
      #pragma unroll
      for (int nt = 0; nt < 4; ++nt)
        acc[mt][nt] = __builtin_amdgcn_mfma_f32_16x16x32_bf16(a[ks & 1][mt], b[nt], acc[mt][nt], 0, 0, 0);
    if (ks < 6) {
      #pragma unroll
      for (int mt = 0; mt < 4; ++mt)
        a[ks & 1][mt] = *(const s16x8*)(w2base + mt * 16 * D_H + (ks + 2) * 32);
    }
  }
  __syncthreads();   // B2: all x1 reads done -> overwrite with x2

  // ---- epilogue 2: relu(+b2) -> x2 bf16 into buf (same swizzle)
  #pragma unroll
  for (int mt = 0; mt < 4; ++mt) {
    int f = wave * 64 + mt * 16 + q * 4;
    float4 bias = *(const float4*)&b2[f];
    #pragma unroll
    for (int nt = 0; nt < 4; ++nt) {
      int nd = nt * 16 + lr;
      u32x2 w;
      w[0] = pkbf(fmaxf(acc[mt][nt][0] + bias.x, 0.f), fmaxf(acc[mt][nt][1] + bias.y, 0.f));
      w[1] = pkbf(fmaxf(acc[mt][nt][2] + bias.z, 0.f), fmaxf(acc[mt][nt][3] + bias.w, 0.f));
      *(u32x2*)&buf[nd * D_H + (((f >> 3) ^ (nd & 7)) << 3) + (f & 7)] = w;
    }
  }

  // ---- pooling (vectorized): thread reads 4 consecutive features of its OWN
  //      wave's stripe (same-wave LDS program order, no barrier); 4 row-groups
  //      of 16 rows per wave -> 16 iterations of b64 reads (was 64 scalar).
  {
    const int f0  = wave * 64 + (lane & 15) * 4;   // own wave's features
    const int rg  = lane >> 4;                     // row-group: 16 rows each
    const int swz = f0 >> 3;
    const int sub = f0 & 7;                        // 0 or 4 -> 8 B aligned
    float ra0 = 0.f, ra1 = 0.f, ra2 = 0.f, ra3 = 0.f;
    for (int rr = 0; rr < 16; ++rr) {
      int r = rg * 16 + rr;
      int g = sgid[r];
      if (g >= 0) {
        u32x2 wv = *(const u32x2*)&buf[r * D_H + ((swz ^ (r & 7)) << 3) + sub];
        ra0 += bf2f((unsigned short)(wv[0] & 0xffffu));
        ra1 += bf2f((unsigned short)(wv[0] >> 16));
        ra2 += bf2f((unsigned short)(wv[1] & 0xffffu));
        ra3 += bf2f((unsigned short)(wv[1] >> 16));
        if (rr == 15 || sgid[r + 1] != g) {        // run boundary (or window end)
          float* dst = &pooled[g * D_H + f0];
          atomicAdd(dst + 0, ra0);
          atomicAdd(dst + 1, ra1);
          atomicAdd(dst + 2, ra2);
          atomicAdd(dst + 3, ra3);
          ra0 = ra1 = ra2 = ra3 = 0.f;
        }
      }
    }
  }
}

// ---------------- graph MLP: swizzled 32 KB LDS, bf16 y, conflict-free ----------------
__global__ __launch_bounds__(256, 4)
void graph_kernel(const float* __restrict__ pooled, const float* __restrict__ bg1,
                  const unsigned short* __restrict__ Wg1t, const float* __restrict__ Wg2,
                  const float* __restrict__ bg2, float* __restrict__ out, int ngraphs) {
  __shared__ unsigned short pA[BMG * D_H];   // 32 KB swizzled; pooled-bf16 then y-bf16
  const int tid  = threadIdx.x;
  const int lane = tid & 63;
  const int wave = tid >> 6;
  const int lr   = lane & 15;
  const int q    = lane >> 4;
  const int g0   = blockIdx.x * BMG;

  #pragma unroll
  for (int i = 0; i < 8; ++i) {
    int gi = tid + i * 256, r = gi >> 5, gc = gi & 31;
    int gr = g0 + r;
    f32x4 v0 = (f32x4){0.f, 0.f, 0.f, 0.f}, v1 = v0;
    if (gr < ngraphs) {
      const f32x4* p = (const f32x4*)(pooled + (size_t)gr * D_H + gc * 8);
      v0 = p[0]; v1 = p[1];
    }
    u32x4 u;
    u[0] = pkbf(v0[0], v0[1]); u[1] = pkbf(v0[2], v0[3]);
    u[2] = pkbf(v1[0], v1[1]); u[3] = pkbf(v1[2], v1[3]);
    *(u32x4*)&pA[r * D_H + (((gc & 7) ^ (r & 7)) << 3) + ((gc & 24) << 3)] = u;
  }
  __syncthreads();

  f32x4 acc[4][4];
  #pragma unroll
  for (int mt = 0; mt < 4; ++mt)
    #pragma unroll
    for (int nt = 0; nt < 4; ++nt)
      acc[mt][nt] = (f32x4){0.f, 0.f, 0.f, 0.f};

  #pragma unroll
  for (int ks = 0; ks < 8; ++ks) {
    const int kq = ks * 32 + q * 8;
    s16x8 a[4], b[4];
    #pragma unroll
    for (int mt = 0; mt < 4; ++mt)
      a[mt] = *(const s16x8*)&Wg1t[(wave * 64 + mt * 16 + lr) * D_H + kq];
    #pragma unroll
    for (int nt = 0; nt < 4; ++nt) {
      int row = nt * 16 + lr, gw = kq >> 3;
      b[nt] = *(const s16x8*)&pA[row * D_H + (((gw & 7) ^ (row & 7)) << 3) + ((gw & 24) << 3)];
    }
    #pragma unroll
    for (int mt = 0; mt < 4; ++mt)
      #pragma unroll
      for (int nt = 0; nt < 4; ++nt)
        acc[mt][nt] = __builtin_amdgcn_mfma_f32_16x16x32_bf16(a[mt], b[nt], acc[mt][nt], 0, 0, 0);
  }
  __syncthreads();   // all pA reads done; overwrite with y

  #pragma unroll
  for (int mt = 0; mt < 4; ++mt) {
    int f = wave * 64 + mt * 16 + q * 4;
    float4 bias = *(const float4*)&bg1[f];
    #pragma unroll
    for (int nt = 0; nt < 4; ++nt) {
      int nd = nt * 16 + lr;
      u32x2 w;
      w[0] = pkbf(fmaxf(acc[mt][nt][0] + bias.x, 0.f), fmaxf(acc[mt][nt][1] + bias.y, 0.f));
      w[1] = pkbf(fmaxf(acc[mt][nt][2] + bias.z, 0.f), fmaxf(acc[mt][nt][3] + bias.w, 0.f));
      int gw = f >> 3;
      *(u32x2*)&pA[nd * D_H + (((gw & 7) ^ (nd & 7)) << 3) + ((gw & 24) << 3) + (f & 7)] = w;
    }
  }
  __syncthreads();

  int gloc = tid >> 2;
  int part = tid & 3;
  float p = 0.f;
  #pragma unroll 8
  for (int i = 0; i < 32; ++i) {
    int f2 = part + 4 * i;
    int hw = 2 * f2;
    int gw = hw >> 3;
    uint32_t wv = *(const uint32_t*)&pA[gloc * D_H + (((gw & 7) ^ (gloc & 7)) << 3) +
                                        ((gw & 24) << 3) + (hw & 7)];
    float2 wg = ((const float2*)Wg2)[f2];
    p += bf2f((unsigned short)(wv & 0xffffu)) * wg.x +
         bf2f((unsigned short)(wv >> 16)) * wg.y;
  }
  p += __shfl_xor(p, 1);
  p += __shfl_xor(p, 2);
  if (part == 0 && (g0 + gloc) < ngraphs)
    out[g0 + gloc] = p + bg2[0];
}

extern "C" void kernel_launch(void* const* d_in, const int* in_sizes, int n_in,
                              void* d_out, int out_size, void* d_ws, size_t ws_size,
                              hipStream_t stream) {
  const float* h   = (const float*)d_in[0];
  const int*   gid = (const int*)d_in[1];
  const float* W1  = (const float*)d_in[3];
  const float* b1  = (const float*)d_in[4];
  const float* W2  = (const float*)d_in[5];
  const float* b2  = (const float*)d_in[6];
  const float* Wg1 = (const float*)d_in[7];
  const float* bg1 = (const float*)d_in[8];
  const float* Wg2 = (const float*)d_in[9];
  const float* bg2 = (const float*)d_in[10];
  float* out = (float*)d_out;

  const int N = in_sizes[1];
  const int G = out_size;

  char* ws = (char*)d_ws;
  float* pooled = (float*)ws;                                   // G*256*4 = 20.48 MB
  size_t off = (size_t)G * D_H * sizeof(float);
  unsigned short* W1t  = (unsigned short*)(ws + off); off += (size_t)D_H * D_IN * 2;
  unsigned short* W2t  = (unsigned short*)(ws + off); off += (size_t)D_H * D_H * 2;
  unsigned short* Wg1t = (unsigned short*)(ws + off);

  prep_kernel<<<512, 256, 0, stream>>>(W1, W2, Wg1, pooled, W1t, W2t, Wg1t, G * D_H);
  node_kernel<<<(N + BM - 1) / BM, 256, 0, stream>>>(h, gid, b1, b2, W1t, W2t, pooled, N);
  graph_kernel<<<(G + BMG - 1) / BMG, 256, 0, stream>>>(pooled, bg1, Wg1t, Wg2, bg2, out, G);
}

// Round 5
// 619.938 us; speedup vs baseline: 1.5338x; 1.0223x over previous
//
#include <hip/hip_runtime.h>
#include <stdint.h>

#define D_IN 128
#define D_H  256
#define BM   64     // node row tile (R0-proven; BM=32 regressed: ~8.2k cy fixed cost/block)
#define BMG  64     // graph-kernel tile

typedef float f32x4 __attribute__((ext_vector_type(4)));
typedef short s16x8 __attribute__((ext_vector_type(8)));
typedef unsigned int u32x2 __attribute__((ext_vector_type(2)));
typedef unsigned int u32x4 __attribute__((ext_vector_type(4)));

__device__ __forceinline__ unsigned short f2bf(float x) {
  union { float f; uint32_t u; } v; v.f = x;
  uint32_t r = v.u + 0x7fffu + ((v.u >> 16) & 1u);   // RNE
  return (unsigned short)(r >> 16);
}
__device__ __forceinline__ float bf2f(unsigned short u) {
  union { uint32_t u; float f; } v; v.u = (uint32_t)u << 16;
  return v.f;
}
// pack 2 fp32 -> 2 bf16 (RNE), HW instruction when available
__device__ __forceinline__ uint32_t pkbf(float lo, float hi) {
#if __has_builtin(__builtin_amdgcn_cvt_pk_bf16_f32)
  auto r = __builtin_amdgcn_cvt_pk_bf16_f32(lo, hi);
  uint32_t u; __builtin_memcpy(&u, &r, 4); return u;
#else
  return (uint32_t)f2bf(lo) | ((uint32_t)f2bf(hi) << 16);
#endif
}

// ---------------- prep: zero pooled accumulator, cast/transpose weights ----------------
__global__ void prep_kernel(const float* __restrict__ W1, const float* __restrict__ W2,
                            const float* __restrict__ Wg1,
                            float* __restrict__ pooled, unsigned short* __restrict__ W1t,
                            unsigned short* __restrict__ W2t, unsigned short* __restrict__ Wg1t,
                            int pooled_n) {
  int stride = gridDim.x * blockDim.x;
  int tid = blockIdx.x * blockDim.x + threadIdx.x;
  float4 z4 = make_float4(0.f, 0.f, 0.f, 0.f);
  for (int i = tid; i < (pooled_n >> 2); i += stride) ((float4*)pooled)[i] = z4;
  for (int i = tid; i < D_H * D_IN; i += stride) {
    int n = i >> 7, k = i & (D_IN - 1);
    W1t[i] = f2bf(W1[k * D_H + n]);
  }
  for (int i = tid; i < D_H * D_H; i += stride) {
    int n = i >> 8, k = i & (D_H - 1);
    W2t[i]  = f2bf(W2[k * D_H + n]);
    Wg1t[i] = f2bf(Wg1[k * D_H + n]);
  }
}

// ---------------- node MLP + fused segment-sum (R0 structure, true 4 blocks/CU) ----------------
// R4 post-mortem: (256,4) spilled because a[2][4](32) + b[4] all-live(16) + acc(64 AGPR)
// + temps > 128 (VGPR clamped 64, WRITE_SIZE 225 MB scratch). Fix: nt-outer/mt-inner
// MFMA order -> only ~2 b-frags live (8 regs), demand ~114 <= 128. Everything else is
// the R0-proven BM=64 schedule: 33 KB LDS (hA aliases buf upper half), barriers
// B0/B1'/B1/B2, same swizzles. Pooling is R4's vectorized version (proven correct).
__global__ __launch_bounds__(256, 4)
void node_kernel(const float* __restrict__ h, const int* __restrict__ gids,
                 const float* __restrict__ b1, const float* __restrict__ b2,
                 const unsigned short* __restrict__ W1t, const unsigned short* __restrict__ W2t,
                 float* __restrict__ pooled, int nnodes) {
  __shared__ unsigned short buf[BM * D_H];   // 32 KB: x1/x2 full; hA = buf[8192..16384)
  __shared__ int sgid[BM];
  const int tid  = threadIdx.x;
  const int lane = tid & 63;
  const int wave = tid >> 6;
  const int lr   = lane & 15;   // row-in-16 (A) / col-in-16 (B,C)
  const int q    = lane >> 4;   // quad
  const int row0 = blockIdx.x * BM;
  unsigned short* hA = buf + 8192;

  const unsigned short* w1base = W1t + (wave * 64 + lr) * D_IN + q * 8;
  const unsigned short* w2base = W2t + (wave * 64 + lr) * D_H + q * 8;

  // ---- rotating 2-deep weight fragment buffer (32 VGPR; R3/R4-proven rotation)
  s16x8 a[2][4];
  #pragma unroll
  for (int mt = 0; mt < 4; ++mt) a[0][mt] = *(const s16x8*)(w1base + mt * 16 * D_IN + 0 * 32);
  #pragma unroll
  for (int mt = 0; mt < 4; ++mt) a[1][mt] = *(const s16x8*)(w1base + mt * 16 * D_IN + 1 * 32);

  if (tid < BM) {
    int gr = row0 + tid;
    sgid[tid] = (gr < nnodes) ? gids[gr] : -1;   // -1 rows excluded from pooling
  }

  // ---- stage h tile (fp32 -> bf16) into swizzled hA
  #pragma unroll
  for (int i = 0; i < 4; ++i) {
    int gi = tid + i * 256, r = gi >> 4, gc = gi & 15, gr = row0 + r;
    f32x4 v0 = (f32x4){0.f, 0.f, 0.f, 0.f}, v1 = v0;
    if (gr < nnodes) {
      const f32x4* p = (const f32x4*)(h + (size_t)gr * D_IN + gc * 8);
      v0 = __builtin_nontemporal_load(p);       // h is read-once
      v1 = __builtin_nontemporal_load(p + 1);
    }
    u32x4 u;
    u[0] = pkbf(v0[0], v0[1]); u[1] = pkbf(v0[2], v0[3]);
    u[2] = pkbf(v1[0], v1[1]); u[3] = pkbf(v1[2], v1[3]);
    *(u32x4*)&hA[r * D_IN + ((gc ^ (r & 7)) << 3)] = u;
  }
  __syncthreads();   // B0: hA published

  f32x4 acc[4][4];
  #pragma unroll
  for (int mt = 0; mt < 4; ++mt)
    #pragma unroll
    for (int nt = 0; nt < 4; ++nt)
      acc[mt][nt] = (f32x4){0.f, 0.f, 0.f, 0.f};

  // ---- layer 1: x1^T = W1^T(256x128) @ h^T(128x64); nt-outer keeps 1-2 b live.
  //      Rotation: ks=0,1 refill W1 ks+2; ks=2,3 refill W2 ks=0,1 (spans B1'+epi1+B1)
  #pragma unroll
  for (int ks = 0; ks < 4; ++ks) {
    const int kq = ks * 32 + q * 8;
    #pragma unroll
    for (int nt = 0; nt < 4; ++nt) {
      s16x8 b = *(const s16x8*)&hA[(nt * 16 + lr) * D_IN + (((kq >> 3) ^ (lr & 7)) << 3)];
      #pragma unroll
      for (int mt = 0; mt < 4; ++mt)
        acc[mt][nt] = __builtin_amdgcn_mfma_f32_16x16x32_bf16(a[ks & 1][mt], b, acc[mt][nt], 0, 0, 0);
    }
    if (ks < 2) {
      #pragma unroll
      for (int mt = 0; mt < 4; ++mt)
        a[ks & 1][mt] = *(const s16x8*)(w1base + mt * 16 * D_IN + (ks + 2) * 32);
    } else {
      #pragma unroll
      for (int mt = 0; mt < 4; ++mt)
        a[ks & 1][mt] = *(const s16x8*)(w2base + mt * 16 * D_H + (ks - 2) * 32);
    }
  }

  __syncthreads();   // B1': all hA reads done -> epi1 may overwrite hA region

  // ---- epilogue 1: relu(+b1) -> x1 bf16 swizzled (full 32 KB buf, incl. hA bytes)
  #pragma unroll
  for (int mt = 0; mt < 4; ++mt) {
    int f = wave * 64 + mt * 16 + q * 4;
    float4 bias = *(const float4*)&b1[f];
    #pragma unroll
    for (int nt = 0; nt < 4; ++nt) {
      int nd = nt * 16 + lr;
      u32x2 w;
      w[0] = pkbf(fmaxf(acc[mt][nt][0] + bias.x, 0.f), fmaxf(acc[mt][nt][1] + bias.y, 0.f));
      w[1] = pkbf(fmaxf(acc[mt][nt][2] + bias.z, 0.f), fmaxf(acc[mt][nt][3] + bias.w, 0.f));
      *(u32x2*)&buf[nd * D_H + (((f >> 3) ^ (nd & 7)) << 3) + (f & 7)] = w;
    }
  }
  __syncthreads();   // B1: x1 published

  #pragma unroll
  for (int mt = 0; mt < 4; ++mt)
    #pragma unroll
    for (int nt = 0; nt < 4; ++nt)
      acc[mt][nt] = (f32x4){0.f, 0.f, 0.f, 0.f};

  // ---- layer 2: 8 unified k-steps; a[ks&1] holds W2 ks (prefetched 2 ahead)
  #pragma unroll
  for (int ks = 0; ks < 8; ++ks) {
    const int kq = ks * 32 + q * 8;
    #pragma unroll
    for (int nt = 0; nt < 4; ++nt) {
      s16x8 b = *(const s16x8*)&buf[(nt * 16 + lr) * D_H + (((kq >> 3) ^ (lr & 7)) << 3)];
      #pragma unroll
      for (int mt = 0; mt < 4; ++mt)
        acc[mt][nt] = __builtin_amdgcn_mfma_f32_16x16x32_bf16(a[ks & 1][mt], b, acc[mt][nt], 0, 0, 0);
    }
    if (ks < 6) {
      #pragma unroll
      for (int mt = 0; mt < 4; ++mt)
        a[ks & 1][mt] = *(const s16x8*)(w2base + mt * 16 * D_H + (ks + 2) * 32);
    }
  }
  __syncthreads();   // B2: all x1 reads done -> overwrite with x2

  // ---- epilogue 2: relu(+b2) -> x2 bf16 into buf (same swizzle)
  #pragma unroll
  for (int mt = 0; mt < 4; ++mt) {
    int f = wave * 64 + mt * 16 + q * 4;
    float4 bias = *(const float4*)&b2[f];
    #pragma unroll
    for (int nt = 0; nt < 4; ++nt) {
      int nd = nt * 16 + lr;
      u32x2 w;
      w[0] = pkbf(fmaxf(acc[mt][nt][0] + bias.x, 0.f), fmaxf(acc[mt][nt][1] + bias.y, 0.f));
      w[1] = pkbf(fmaxf(acc[mt][nt][2] + bias.z, 0.f), fmaxf(acc[mt][nt][3] + bias.w, 0.f));
      *(u32x2*)&buf[nd * D_H + (((f >> 3) ^ (nd & 7)) << 3) + (f & 7)] = w;
    }
  }

  // ---- pooling (vectorized, R4-proven): thread reads 4 consecutive features of
  //      its OWN wave's stripe (same-wave LDS program order, no barrier);
  //      4 row-groups of 16 rows per wave -> 16 b64 iterations (was 64 scalar).
  {
    const int f0  = wave * 64 + (lane & 15) * 4;   // own wave's features
    const int rg  = lane >> 4;                     // row-group: 16 rows each
    const int swz = f0 >> 3;
    const int sub = f0 & 7;                        // 0 or 4 -> 8 B aligned
    float ra0 = 0.f, ra1 = 0.f, ra2 = 0.f, ra3 = 0.f;
    for (int rr = 0; rr < 16; ++rr) {
      int r = rg * 16 + rr;
      int g = sgid[r];
      if (g >= 0) {
        u32x2 wv = *(const u32x2*)&buf[r * D_H + ((swz ^ (r & 7)) << 3) + sub];
        ra0 += bf2f((unsigned short)(wv[0] & 0xffffu));
        ra1 += bf2f((unsigned short)(wv[0] >> 16));
        ra2 += bf2f((unsigned short)(wv[1] & 0xffffu));
        ra3 += bf2f((unsigned short)(wv[1] >> 16));
        if (rr == 15 || sgid[r + 1] != g) {        // run boundary (or window end)
          float* dst = &pooled[g * D_H + f0];
          atomicAdd(dst + 0, ra0);
          atomicAdd(dst + 1, ra1);
          atomicAdd(dst + 2, ra2);
          atomicAdd(dst + 3, ra3);
          ra0 = ra1 = ra2 = ra3 = 0.f;
        }
      }
    }
  }
}

// ---------------- graph MLP: swizzled 32 KB LDS, bf16 y, conflict-free ----------------
__global__ __launch_bounds__(256, 4)
void graph_kernel(const float* __restrict__ pooled, const float* __restrict__ bg1,
                  const unsigned short* __restrict__ Wg1t, const float* __restrict__ Wg2,
                  const float* __restrict__ bg2, float* __restrict__ out, int ngraphs) {
  __shared__ unsigned short pA[BMG * D_H];   // 32 KB swizzled; pooled-bf16 then y-bf16
  const int tid  = threadIdx.x;
  const int lane = tid & 63;
  const int wave = tid >> 6;
  const int lr   = lane & 15;
  const int q    = lane >> 4;
  const int g0   = blockIdx.x * BMG;

  #pragma unroll
  for (int i = 0; i < 8; ++i) {
    int gi = tid + i * 256, r = gi >> 5, gc = gi & 31;
    int gr = g0 + r;
    f32x4 v0 = (f32x4){0.f, 0.f, 0.f, 0.f}, v1 = v0;
    if (gr < ngraphs) {
      const f32x4* p = (const f32x4*)(pooled + (size_t)gr * D_H + gc * 8);
      v0 = p[0]; v1 = p[1];
    }
    u32x4 u;
    u[0] = pkbf(v0[0], v0[1]); u[1] = pkbf(v0[2], v0[3]);
    u[2] = pkbf(v1[0], v1[1]); u[3] = pkbf(v1[2], v1[3]);
    *(u32x4*)&pA[r * D_H + (((gc & 7) ^ (r & 7)) << 3) + ((gc & 24) << 3)] = u;
  }
  __syncthreads();

  f32x4 acc[4][4];
  #pragma unroll
  for (int mt = 0; mt < 4; ++mt)
    #pragma unroll
    for (int nt = 0; nt < 4; ++nt)
      acc[mt][nt] = (f32x4){0.f, 0.f, 0.f, 0.f};

  #pragma unroll
  for (int ks = 0; ks < 8; ++ks) {
    const int kq = ks * 32 + q * 8;
    s16x8 a[4], b[4];
    #pragma unroll
    for (int mt = 0; mt < 4; ++mt)
      a[mt] = *(const s16x8*)&Wg1t[(wave * 64 + mt * 16 + lr) * D_H + kq];
    #pragma unroll
    for (int nt = 0; nt < 4; ++nt) {
      int row = nt * 16 + lr, gw = kq >> 3;
      b[nt] = *(const s16x8*)&pA[row * D_H + (((gw & 7) ^ (row & 7)) << 3) + ((gw & 24) << 3)];
    }
    #pragma unroll
    for (int mt = 0; mt < 4; ++mt)
      #pragma unroll
      for (int nt = 0; nt < 4; ++nt)
        acc[mt][nt] = __builtin_amdgcn_mfma_f32_16x16x32_bf16(a[mt], b[nt], acc[mt][nt], 0, 0, 0);
  }
  __syncthreads();   // all pA reads done; overwrite with y

  #pragma unroll
  for (int mt = 0; mt < 4; ++mt) {
    int f = wave * 64 + mt * 16 + q * 4;
    float4 bias = *(const float4*)&bg1[f];
    #pragma unroll
    for (int nt = 0; nt < 4; ++nt) {
      int nd = nt * 16 + lr;
      u32x2 w;
      w[0] = pkbf(fmaxf(acc[mt][nt][0] + bias.x, 0.f), fmaxf(acc[mt][nt][1] + bias.y, 0.f));
      w[1] = pkbf(fmaxf(acc[mt][nt][2] + bias.z, 0.f), fmaxf(acc[mt][nt][3] + bias.w, 0.f));
      int gw = f >> 3;
      *(u32x2*)&pA[nd * D_H + (((gw & 7) ^ (nd & 7)) << 3) + ((gw & 24) << 3) + (f & 7)] = w;
    }
  }
  __syncthreads();

  int gloc = tid >> 2;
  int part = tid & 3;
  float p = 0.f;
  #pragma unroll 8
  for (int i = 0; i < 32; ++i) {
    int f2 = part + 4 * i;
    int hw = 2 * f2;
    int gw = hw >> 3;
    uint32_t wv = *(const uint32_t*)&pA[gloc * D_H + (((gw & 7) ^ (gloc & 7)) << 3) +
                                        ((gw & 24) << 3) + (hw & 7)];
    float2 wg = ((const float2*)Wg2)[f2];
    p += bf2f((unsigned short)(wv & 0xffffu)) * wg.x +
         bf2f((unsigned short)(wv >> 16)) * wg.y;
  }
  p += __shfl_xor(p, 1);
  p += __shfl_xor(p, 2);
  if (part == 0 && (g0 + gloc) < ngraphs)
    out[g0 + gloc] = p + bg2[0];
}

extern "C" void kernel_launch(void* const* d_in, const int* in_sizes, int n_in,
                              void* d_out, int out_size, void* d_ws, size_t ws_size,
                              hipStream_t stream) {
  const float* h   = (const float*)d_in[0];
  const int*   gid = (const int*)d_in[1];
  const float* W1  = (const float*)d_in[3];
  const float* b1  = (const float*)d_in[4];
  const float* W2  = (const float*)d_in[5];
  const float* b2  = (const float*)d_in[6];
  const float* Wg1 = (const float*)d_in[7];
  const float* bg1 = (const float*)d_in[8];
  const float* Wg2 = (const float*)d_in[9];
  const float* bg2 = (const float*)d_in[10];
  float* out = (float*)d_out;

  const int N = in_sizes[1];
  const int G = out_size;

  char* ws = (char*)d_ws;
  float* pooled = (float*)ws;                                   // G*256*4 = 20.48 MB
  size_t off = (size_t)G * D_H * sizeof(float);
  unsigned short* W1t  = (unsigned short*)(ws + off); off += (size_t)D_H * D_IN * 2;
  unsigned short* W2t  = (unsigned short*)(ws + off); off += (size_t)D_H * D_H * 2;
  unsigned short* Wg1t = (unsigned short*)(ws + off);

  prep_kernel<<<512, 256, 0, stream>>>(W1, W2, Wg1, pooled, W1t, W2t, Wg1t, G * D_H);
  node_kernel<<<(N + BM - 1) / BM, 256, 0, stream>>>(h, gid, b1, b2, W1t, W2t, pooled, N);
  graph_kernel<<<(G + BMG - 1) / BMG, 256, 0, stream>>>(pooled, bg1, Wg1t, Wg2, bg2, out, G);
}